// Round 7
// baseline (40.847 us; speedup 1.0000x reference)
//
#include <hip/hip_runtime.h>
#include <hip/hip_bf16.h>
#include <math.h>

constexpr int Bn = 1024;   // batch
constexpr int Cn = 1000;   // classes
constexpr int Dn = 256;    // feature dim
constexpr float EPS = 1e-4f;

typedef __attribute__((ext_vector_type(8))) short bf16x8;
typedef __attribute__((ext_vector_type(4))) float f32x4;

// f32 -> bf16 round-to-nearest-even
static __device__ __forceinline__ unsigned short f2bf(float x) {
    union { float f; unsigned u; } v; v.f = x;
    return (unsigned short)((v.u + 0x7fffu + ((v.u >> 16) & 1u)) >> 16);
}
static __device__ __forceinline__ float bf2f(unsigned short h) {
    union { unsigned u; float f; } v; v.u = ((unsigned)h) << 16; return v.f;
}

// Swizzled LDS addressing for a [64][256]-bf16 tile (512 B rows):
// byte ^= (row&7)<<4 spreads the 16-lane row-column frag reads across banks
// (2-way residual conflict = free). Same mapping for ALL writes and reads.
static __device__ __forceinline__ unsigned short* lds_u(unsigned short* base, int row, int b) {
    return (unsigned short*)((char*)base + row * 512 + (b ^ ((row & 7) << 4)));
}
static __device__ __forceinline__ const unsigned short* lds_c(const unsigned short* base, int row, int b) {
    return (const unsigned short*)((const char*)base + row * 512 + (b ^ ((row & 7) << 4)));
}

// ---------------------------------------------------------------------------
// Single flat kernel, 256 blocks x 256 threads, 1 block/CU (LDS-bound).
// Block (r,c): out[r*64..][c*64..] = Y_b.U_c + rowbias + colbias, where
// Y = z@F, U = mu@F are recomputed per block into LDS (redundant 16x, cheap
// at MFMA rate; removes all inter-block deps -> single launch, no workspace).
__global__ __launch_bounds__(256) void lda_one_kernel(const float* __restrict__ z,
                                                      const float* __restrict__ mu,
                                                      const float* __restrict__ logits,
                                                      const float* __restrict__ F,
                                                      float* __restrict__ out) {
    __shared__ unsigned short Zl[64 * 256];   // bf16(z rows)      32 KB
    __shared__ unsigned short Ml[64 * 256];   // bf16(mu rows)     32 KB
    __shared__ unsigned short Yl[64 * 256];   // bf16(Z@F)         32 KB
    __shared__ unsigned short Ul[64 * 256];   // bf16(M@F)         32 KB
    __shared__ float red[64][4];
    __shared__ float rowbias[64], colbias[64];
    __shared__ float rl[256];
    __shared__ float lse_s;

    const int bid = blockIdx.x, tid = threadIdx.x;
    const int row0 = (bid >> 4) * 64;   // z rows
    const int col0 = (bid & 15) * 64;   // classes

    // ---- LSE (redundant per block; identical deterministic order) ----
    {
        float mx = -INFINITY;
        for (int i = tid; i < Cn; i += 256) mx = fmaxf(mx, logits[i]);
        rl[tid] = mx; __syncthreads();
        for (int s = 128; s > 0; s >>= 1) {
            if (tid < s) rl[tid] = fmaxf(rl[tid], rl[tid + s]);
            __syncthreads();
        }
        mx = rl[0]; __syncthreads();
        float sm = 0.f;
        for (int i = tid; i < Cn; i += 256) sm += expf(logits[i] - mx);
        rl[tid] = sm; __syncthreads();
        for (int s = 128; s > 0; s >>= 1) {
            if (tid < s) rl[tid] += rl[tid + s];
            __syncthreads();
        }
        if (tid == 0) lse_s = mx + logf(rl[0]);
    }

    // ---- stage Z and M tiles: f32 global -> bf16 LDS (swizzled) ----
#pragma unroll
    for (int i = 0; i < 16; ++i) {
        const int flat = i * 256 + tid;          // float4 index in [64][64]
        const int r = flat >> 6, c4 = flat & 63;
        const float4 vz = *(const float4*)&z[(size_t)(row0 + r) * Dn + c4 * 4];
        ushort4 sz;
        sz.x = f2bf(vz.x); sz.y = f2bf(vz.y); sz.z = f2bf(vz.z); sz.w = f2bf(vz.w);
        *(ushort4*)lds_u(Zl, r, c4 * 8) = sz;
        const int rm = min(col0 + r, Cn - 1);    // clamp; outputs guarded later
        const float4 vm = *(const float4*)&mu[(size_t)rm * Dn + c4 * 4];
        ushort4 smv;
        smv.x = f2bf(vm.x); smv.y = f2bf(vm.y); smv.z = f2bf(vm.z); smv.w = f2bf(vm.w);
        *(ushort4*)lds_u(Ml, r, c4 * 8) = smv;
    }
    __syncthreads();

    const int lane = tid & 63, w = tid >> 6;
    const int la = lane & 15, kg = lane >> 4;

    // ---- phase B: Y = Z@F, U = M@F (64x32 per (wave,ct)); B-frags gathered
    //      from F (f32, coalesced across the 16 frag lanes) once per ct.
    {
        const int wr = (w >> 1) * 32, wc = (w & 1) * 16;
#pragma unroll 1
        for (int ct = 0; ct < 8; ++ct) {
            const int bcol = ct * 32 + wc + la;
            bf16x8 ball[8];
#pragma unroll
            for (int kt = 0; kt < 8; ++kt) {
                const int k0 = kt * 32 + kg * 8;
                float bf[8];
#pragma unroll
                for (int j = 0; j < 8; ++j) bf[j] = F[(size_t)(k0 + j) * Dn + bcol];
                bf16x8 bb;
#pragma unroll
                for (int j = 0; j < 8; ++j) bb[j] = (short)f2bf(bf[j]);
                ball[kt] = bb;
            }
#pragma unroll
            for (int t = 0; t < 2; ++t) {
                const unsigned short* src = t ? Ml : Zl;
                unsigned short* dst = t ? Ul : Yl;
                f32x4 acc0 = {0.f, 0.f, 0.f, 0.f};
                f32x4 acc1 = {0.f, 0.f, 0.f, 0.f};
#pragma unroll
                for (int kt = 0; kt < 8; ++kt) {
                    const int kb = (kt * 32 + kg * 8) * 2;
                    const bf16x8 a0 = *(const bf16x8*)lds_c(src, wr + la, kb);
                    const bf16x8 a1 = *(const bf16x8*)lds_c(src, wr + 16 + la, kb);
                    acc0 = __builtin_amdgcn_mfma_f32_16x16x32_bf16(a0, ball[kt], acc0, 0, 0, 0);
                    acc1 = __builtin_amdgcn_mfma_f32_16x16x32_bf16(a1, ball[kt], acc1, 0, 0, 0);
                }
                // C/D: col = la (-> bcol), row = kg*4 + j
                const int rb0 = wr + kg * 4;
#pragma unroll
                for (int j = 0; j < 4; ++j) {
                    *lds_u(dst, rb0 + j, bcol * 2)      = f2bf(acc0[j]);
                    *lds_u(dst, rb0 + 16 + j, bcol * 2) = f2bf(acc1[j]);
                }
            }
        }
    }
    __syncthreads();

    // ---- phase C: row/col biases from LDS tiles ----
    {
        const int r = tid >> 2, q = tid & 3;
        float sy = 0.f, sz2 = 0.f;
#pragma unroll
        for (int i = 0; i < 8; ++i) {
            const bf16x8 hy = *(const bf16x8*)lds_c(Yl, r, q * 128 + i * 16);
            const bf16x8 hz = *(const bf16x8*)lds_c(Zl, r, q * 128 + i * 16);
#pragma unroll
            for (int j = 0; j < 8; ++j) {
                const float fy = bf2f((unsigned short)hy[j]);
                const float fz = bf2f((unsigned short)hz[j]);
                sy = fmaf(fy, fy, sy);
                sz2 = fmaf(fz, fz, sz2);
            }
        }
        red[r][q] = sy + EPS * sz2;
        __syncthreads();
        if (tid < 64)
            rowbias[tid] = -0.5f * (red[tid][0] + red[tid][1] + red[tid][2] + red[tid][3]);
        __syncthreads();

        float su = 0.f, sm2 = 0.f;
#pragma unroll
        for (int i = 0; i < 8; ++i) {
            const bf16x8 hu = *(const bf16x8*)lds_c(Ul, r, q * 128 + i * 16);
            const bf16x8 hm = *(const bf16x8*)lds_c(Ml, r, q * 128 + i * 16);
#pragma unroll
            for (int j = 0; j < 8; ++j) {
                const float fu = bf2f((unsigned short)hu[j]);
                const float fm = bf2f((unsigned short)hm[j]);
                su = fmaf(fu, fu, su);
                sm2 = fmaf(fm, fm, sm2);
            }
        }
        red[r][q] = su + EPS * sm2;
        __syncthreads();
        if (tid < 64) {
            const int c = col0 + tid;
            colbias[tid] = (c < Cn)
                ? logits[c] - lse_s - 0.5f * (red[tid][0] + red[tid][1] +
                                              red[tid][2] + red[tid][3])
                : 0.f;
        }
        __syncthreads();
    }

    // ---- phase D: 64x64 output tile (4 waves x 32x32), frags from LDS ----
    const int wr2 = (w >> 1) * 32, wc2 = (w & 1) * 32;

    f32x4 acc00 = {0.f, 0.f, 0.f, 0.f};
    f32x4 acc01 = {0.f, 0.f, 0.f, 0.f};
    f32x4 acc10 = {0.f, 0.f, 0.f, 0.f};
    f32x4 acc11 = {0.f, 0.f, 0.f, 0.f};

#pragma unroll
    for (int kt = 0; kt < 8; ++kt) {
        const int kb = (kt * 32 + kg * 8) * 2;
        const bf16x8 a0 = *(const bf16x8*)lds_c(Yl, wr2 + la, kb);
        const bf16x8 a1 = *(const bf16x8*)lds_c(Yl, wr2 + 16 + la, kb);
        const bf16x8 b0 = *(const bf16x8*)lds_c(Ul, wc2 + la, kb);
        const bf16x8 b1 = *(const bf16x8*)lds_c(Ul, wc2 + 16 + la, kb);
        acc00 = __builtin_amdgcn_mfma_f32_16x16x32_bf16(a0, b0, acc00, 0, 0, 0);
        acc01 = __builtin_amdgcn_mfma_f32_16x16x32_bf16(a0, b1, acc01, 0, 0, 0);
        acc10 = __builtin_amdgcn_mfma_f32_16x16x32_bf16(a1, b0, acc10, 0, 0, 0);
        acc11 = __builtin_amdgcn_mfma_f32_16x16x32_bf16(a1, b1, acc11, 0, 0, 0);
    }

    // C/D layout: col = lane&15, row = kg*4 + j
    const int rbase = kg * 4;
#define EPI(ACC, RF, CF)                                                        \
    do {                                                                        \
        const int gcl = wc2 + (CF)*16 + la;                                     \
        const int gc  = col0 + gcl;                                             \
        if (gc < Cn) {                                                          \
            const float cb = colbias[gcl];                                      \
            _Pragma("unroll")                                                   \
            for (int j = 0; j < 4; ++j) {                                       \
                const int rlc = wr2 + (RF)*16 + rbase + j;                      \
                out[(size_t)(row0 + rlc) * Cn + gc] = ACC[j] + rowbias[rlc] + cb; \
            }                                                                   \
        }                                                                       \
    } while (0)

    EPI(acc00, 0, 0); EPI(acc01, 0, 1); EPI(acc10, 1, 0); EPI(acc11, 1, 1);
#undef EPI
}

// ---------------------------------------------------------------------------
extern "C" void kernel_launch(void* const* d_in, const int* in_sizes, int n_in,
                              void* d_out, int out_size, void* d_ws, size_t ws_size,
                              hipStream_t stream) {
    const float* z      = (const float*)d_in[0];   // [1024][256]
    const float* mu     = (const float*)d_in[1];   // [1000][256]
    const float* logits = (const float*)d_in[2];   // [1000]
    const float* F      = (const float*)d_in[3];   // [256][256]
    float* out = (float*)d_out;                    // [1024][1000]

    lda_one_kernel<<<dim3(256), dim3(256), 0, stream>>>(z, mu, logits, F, out);
}

// Round 8
// 32.280 us; speedup vs baseline: 1.2654x; 1.2654x over previous
//
#include <hip/hip_runtime.h>
#include <hip/hip_bf16.h>
#include <math.h>

constexpr int Bn = 1024;   // batch
constexpr int Cn = 1000;   // classes
constexpr int Dn = 256;    // feature dim
constexpr float EPS = 1e-4f;

typedef __attribute__((ext_vector_type(8))) short bf16x8;
typedef __attribute__((ext_vector_type(4))) float f32x4;

static __device__ __forceinline__ unsigned short f2bf(float x) {
    union { float f; unsigned u; } v; v.f = x;
    return (unsigned short)((v.u + 0x7fffu + ((v.u >> 16) & 1u)) >> 16);
}
static __device__ __forceinline__ float bf2f(unsigned short h) {
    union { unsigned u; float f; } v; v.u = ((unsigned)h) << 16; return v.f;
}
static __device__ __forceinline__ bf16x8 cvt8(const float4 lo, const float4 hi) {
    bf16x8 r;
    r[0] = (short)f2bf(lo.x); r[1] = (short)f2bf(lo.y);
    r[2] = (short)f2bf(lo.z); r[3] = (short)f2bf(lo.w);
    r[4] = (short)f2bf(hi.x); r[5] = (short)f2bf(hi.y);
    r[6] = (short)f2bf(hi.z); r[7] = (short)f2bf(hi.w);
    return r;
}
// Yl/Ul: [64 rows][256 k] bf16 (512 B rows), XOR swizzle on row -> frag reads ~2-way.
static __device__ __forceinline__ char* tile_p(unsigned short* b, int row, int kbyte) {
    return (char*)b + row * 512 + (kbyte ^ ((row & 7) << 4));
}
static __device__ __forceinline__ const char* tile_cp(const unsigned short* b, int row, int kbyte) {
    return (const char*)b + row * 512 + (kbyte ^ ((row & 7) << 4));
}
// Ftl slice: [32 c][256 k] bf16, XOR on c (reads: b128 2-way across 16 lanes).
static __device__ __forceinline__ int ft_off(int c, int kbyte) {
    return c * 512 + (kbyte ^ ((c & 7) << 4));
}

// ---------------------------------------------------------------------------
// Single flat kernel, 256 blocks x 256 threads.
// Block (r,c): out[64x64] tile. Per block: A-stripes of z/mu in REGISTERS
// (ct-invariant), F^T staged per-32-col-slice in LDS with T14 prefetch,
// Y/U tiles built in LDS via MFMA, norms accumulated in-register,
// then the 64x64 NT MFMA + fused bias epilogue (verified R7 code).
__global__ __launch_bounds__(256) void lda_fused2(const float* __restrict__ z,
                                                  const float* __restrict__ mu,
                                                  const float* __restrict__ logits,
                                                  const float* __restrict__ F,
                                                  float* __restrict__ out) {
    __shared__ unsigned short Yl[64 * 256];   // 32 KB
    __shared__ unsigned short Ul[64 * 256];   // 32 KB
    __shared__ unsigned short Ftl[32 * 256];  // 16 KB (F^T slice)
    __shared__ float zn[64], mn[64], nY[2][64], nU[2][64];
    __shared__ float rowbias[64], colbias[64];

    const int bid = blockIdx.x, tid = threadIdx.x;
    const int row0 = (bid >> 4) * 64;   // z rows
    const int col0 = (bid & 15) * 64;   // classes
    const int lane = tid & 63, w = tid >> 6;
    const int la = lane & 15, kg = lane >> 4;
    const int wr = (w >> 1) * 32, wc = (w & 1) * 16;

    // ---- A preload: this wave's z/mu stripes -> bf16 registers (ct-invariant)
    const float* zr0 = &z[(size_t)(row0 + wr + la) * Dn];
    const float* zr1 = zr0 + 16 * Dn;
    const float* mr0 = &mu[(size_t)min(col0 + wr + la, Cn - 1) * Dn];
    const float* mr1 = &mu[(size_t)min(col0 + wr + 16 + la, Cn - 1) * Dn];
    bf16x8 az0[8], az1[8], am0[8], am1[8];
#pragma unroll
    for (int kt = 0; kt < 8; ++kt) {
        const int k0 = kt * 32 + kg * 8;
        az0[kt] = cvt8(*(const float4*)&zr0[k0], *(const float4*)&zr0[k0 + 4]);
        az1[kt] = cvt8(*(const float4*)&zr1[k0], *(const float4*)&zr1[k0 + 4]);
        am0[kt] = cvt8(*(const float4*)&mr0[k0], *(const float4*)&mr0[k0 + 4]);
        am1[kt] = cvt8(*(const float4*)&mr1[k0], *(const float4*)&mr1[k0 + 4]);
    }

    // ---- per-wave LSE (shuffle-only, no barriers)
    float mx = -INFINITY;
    for (int i = lane; i < Cn; i += 64) mx = fmaxf(mx, logits[i]);
#pragma unroll
    for (int off = 32; off > 0; off >>= 1) mx = fmaxf(mx, __shfl_xor(mx, off));
    float sm = 0.f;
    for (int i = lane; i < Cn; i += 64) sm += expf(logits[i] - mx);
#pragma unroll
    for (int off = 32; off > 0; off >>= 1) sm += __shfl_xor(sm, off);
    const float lse = mx + logf(sm);

    // ---- eps-norms of z/mu rows from the bf16 regs (kg-lanes partition k)
    {
        float s0 = 0.f, s1 = 0.f, s2 = 0.f, s3 = 0.f;
#pragma unroll
        for (int kt = 0; kt < 8; ++kt)
#pragma unroll
            for (int j = 0; j < 8; ++j) {
                const float a = bf2f((unsigned short)az0[kt][j]); s0 = fmaf(a, a, s0);
                const float b = bf2f((unsigned short)az1[kt][j]); s1 = fmaf(b, b, s1);
                const float c = bf2f((unsigned short)am0[kt][j]); s2 = fmaf(c, c, s2);
                const float d = bf2f((unsigned short)am1[kt][j]); s3 = fmaf(d, d, s3);
            }
        s0 += __shfl_xor(s0, 16); s0 += __shfl_xor(s0, 32);
        s1 += __shfl_xor(s1, 16); s1 += __shfl_xor(s1, 32);
        s2 += __shfl_xor(s2, 16); s2 += __shfl_xor(s2, 32);
        s3 += __shfl_xor(s3, 16); s3 += __shfl_xor(s3, 32);
        if ((w & 1) == 0 && kg == 0) {   // waves 0,2; lanes 0..15 (w=1,3 identical)
            zn[wr + la] = s0; zn[wr + 16 + la] = s1;
            mn[wr + la] = s2; mn[wr + 16 + la] = s3;
        }
    }

    // ---- phase B: Y = Z@F, U = M@F, with per-ct F^T LDS slice + prefetch
    const int ch = tid >> 7, kp = tid & 127;   // F-stage mapping: rows 2kp,2kp+1; 16-col half ch
    float4 fa[4], fb[4];
    {
        const float* p0 = &F[(size_t)(2 * kp) * Dn + ch * 16];
        const float* p1 = p0 + Dn;
#pragma unroll
        for (int cc = 0; cc < 4; ++cc) {
            fa[cc] = *(const float4*)&p0[cc * 4];
            fb[cc] = *(const float4*)&p1[cc * 4];
        }
    }
    float ny0[4] = {}, ny1[4] = {}, nu0[4] = {}, nu1[4] = {};

#pragma unroll 1
    for (int ct = 0; ct < 8; ++ct) {
        __syncthreads();                      // prev Ftl readers done
        // write current slice regs -> Ftl (2-way banks, free)
#pragma unroll
        for (int cc = 0; cc < 4; ++cc) {
            const float* a = (const float*)&fa[cc];
            const float* b = (const float*)&fb[cc];
#pragma unroll
            for (int e = 0; e < 4; ++e) {
                const int c = ch * 16 + cc * 4 + e;
                ushort2 v; v.x = f2bf(a[e]); v.y = f2bf(b[e]);
                *(ushort2*)((char*)Ftl + ft_off(c, 4 * kp)) = v;
            }
        }
        __syncthreads();
        // prefetch next slice (loads overlap the MFMA below)
        if (ct < 7) {
            const float* p0 = &F[(size_t)(2 * kp) * Dn + (ct + 1) * 32 + ch * 16];
            const float* p1 = p0 + Dn;
#pragma unroll
            for (int cc = 0; cc < 4; ++cc) {
                fa[cc] = *(const float4*)&p0[cc * 4];
                fb[cc] = *(const float4*)&p1[cc * 4];
            }
        }
        // B-frags for this wave's 16 cols of the slice
        bf16x8 bfr[8];
#pragma unroll
        for (int kt = 0; kt < 8; ++kt)
            bfr[kt] = *(const bf16x8*)((const char*)Ftl + ft_off(wc + la, (kt * 32 + kg * 8) * 2));

        const int bcol = ct * 32 + wc + la;   // global W col
        const int rb0 = wr + kg * 4;
        {   // t = 0: Y
            f32x4 acc0 = {0.f, 0.f, 0.f, 0.f}, acc1 = {0.f, 0.f, 0.f, 0.f};
#pragma unroll
            for (int kt = 0; kt < 8; ++kt) {
                acc0 = __builtin_amdgcn_mfma_f32_16x16x32_bf16(az0[kt], bfr[kt], acc0, 0, 0, 0);
                acc1 = __builtin_amdgcn_mfma_f32_16x16x32_bf16(az1[kt], bfr[kt], acc1, 0, 0, 0);
            }
#pragma unroll
            for (int j = 0; j < 4; ++j) {
                const unsigned short h0 = f2bf(acc0[j]), h1 = f2bf(acc1[j]);
                *(unsigned short*)tile_p(Yl, rb0 + j, bcol * 2)      = h0;
                *(unsigned short*)tile_p(Yl, rb0 + 16 + j, bcol * 2) = h1;
                const float y0 = bf2f(h0), y1 = bf2f(h1);
                ny0[j] = fmaf(y0, y0, ny0[j]); ny1[j] = fmaf(y1, y1, ny1[j]);
            }
        }
        {   // t = 1: U
            f32x4 acc0 = {0.f, 0.f, 0.f, 0.f}, acc1 = {0.f, 0.f, 0.f, 0.f};
#pragma unroll
            for (int kt = 0; kt < 8; ++kt) {
                acc0 = __builtin_amdgcn_mfma_f32_16x16x32_bf16(am0[kt], bfr[kt], acc0, 0, 0, 0);
                acc1 = __builtin_amdgcn_mfma_f32_16x16x32_bf16(am1[kt], bfr[kt], acc1, 0, 0, 0);
            }
#pragma unroll
            for (int j = 0; j < 4; ++j) {
                const unsigned short h0 = f2bf(acc0[j]), h1 = f2bf(acc1[j]);
                *(unsigned short*)tile_p(Ul, rb0 + j, bcol * 2)      = h0;
                *(unsigned short*)tile_p(Ul, rb0 + 16 + j, bcol * 2) = h1;
                const float u0 = bf2f(h0), u1 = bf2f(h1);
                nu0[j] = fmaf(u0, u0, nu0[j]); nu1[j] = fmaf(u1, u1, nu1[j]);
            }
        }
    }

    // ---- reduce Y/U row-norm partials over the 16 la-lanes
#pragma unroll
    for (int j = 0; j < 4; ++j)
#pragma unroll
        for (int m = 1; m < 16; m <<= 1) {
            ny0[j] += __shfl_xor(ny0[j], m); ny1[j] += __shfl_xor(ny1[j], m);
            nu0[j] += __shfl_xor(nu0[j], m); nu1[j] += __shfl_xor(nu1[j], m);
        }
    if (la == 0) {
#pragma unroll
        for (int j = 0; j < 4; ++j) {
            nY[w & 1][wr + kg * 4 + j]      = ny0[j];
            nY[w & 1][wr + 16 + kg * 4 + j] = ny1[j];
            nU[w & 1][wr + kg * 4 + j]      = nu0[j];
            nU[w & 1][wr + 16 + kg * 4 + j] = nu1[j];
        }
    }
    __syncthreads();

    if (tid < 64) {
        rowbias[tid] = -0.5f * (nY[0][tid] + nY[1][tid] + EPS * zn[tid]);
    } else if (tid < 128) {
        const int lc = tid - 64, c = col0 + lc;
        colbias[lc] = (c < Cn)
            ? logits[c] - lse - 0.5f * (nU[0][lc] + nU[1][lc] + EPS * mn[lc])
            : 0.f;
    }
    __syncthreads();

    // ---- phase D: 64x64 output tile (verified R7 code) ----
    const int wr2 = (w >> 1) * 32, wc2 = (w & 1) * 32;
    f32x4 acc00 = {0.f, 0.f, 0.f, 0.f};
    f32x4 acc01 = {0.f, 0.f, 0.f, 0.f};
    f32x4 acc10 = {0.f, 0.f, 0.f, 0.f};
    f32x4 acc11 = {0.f, 0.f, 0.f, 0.f};

#pragma unroll
    for (int kt = 0; kt < 8; ++kt) {
        const int kb = (kt * 32 + kg * 8) * 2;
        const bf16x8 a0 = *(const bf16x8*)tile_cp(Yl, wr2 + la, kb);
        const bf16x8 a1 = *(const bf16x8*)tile_cp(Yl, wr2 + 16 + la, kb);
        const bf16x8 b0 = *(const bf16x8*)tile_cp(Ul, wc2 + la, kb);
        const bf16x8 b1 = *(const bf16x8*)tile_cp(Ul, wc2 + 16 + la, kb);
        acc00 = __builtin_amdgcn_mfma_f32_16x16x32_bf16(a0, b0, acc00, 0, 0, 0);
        acc01 = __builtin_amdgcn_mfma_f32_16x16x32_bf16(a0, b1, acc01, 0, 0, 0);
        acc10 = __builtin_amdgcn_mfma_f32_16x16x32_bf16(a1, b0, acc10, 0, 0, 0);
        acc11 = __builtin_amdgcn_mfma_f32_16x16x32_bf16(a1, b1, acc11, 0, 0, 0);
    }

    // C/D layout: col = lane&15, row = kg*4 + j
    const int rbase = kg * 4;
#define EPI(ACC, RF, CF)                                                        \
    do {                                                                        \
        const int gcl = wc2 + (CF)*16 + la;                                     \
        const int gc  = col0 + gcl;                                             \
        if (gc < Cn) {                                                          \
            const float cb = colbias[gcl];                                      \
            _Pragma("unroll")                                                   \
            for (int j = 0; j < 4; ++j) {                                       \
                const int rlc = wr2 + (RF)*16 + rbase + j;                      \
                out[(size_t)(row0 + rlc) * Cn + gc] = ACC[j] + rowbias[rlc] + cb; \
            }                                                                   \
        }                                                                       \
    } while (0)

    EPI(acc00, 0, 0); EPI(acc01, 0, 1); EPI(acc10, 1, 0); EPI(acc11, 1, 1);
#undef EPI
}

// ---------------------------------------------------------------------------
extern "C" void kernel_launch(void* const* d_in, const int* in_sizes, int n_in,
                              void* d_out, int out_size, void* d_ws, size_t ws_size,
                              hipStream_t stream) {
    const float* z      = (const float*)d_in[0];   // [1024][256]
    const float* mu     = (const float*)d_in[1];   // [1000][256]
    const float* logits = (const float*)d_in[2];   // [1000]
    const float* F      = (const float*)d_in[3];   // [256][256]
    float* out = (float*)d_out;                    // [1024][1000]

    lda_fused2<<<dim3(256), dim3(256), 0, stream>>>(z, mu, logits, F, out);
}

// Round 9
// 31.238 us; speedup vs baseline: 1.3076x; 1.0334x over previous
//
#include <hip/hip_runtime.h>
#include <hip/hip_bf16.h>
#include <math.h>

constexpr int Bn = 1024;   // batch
constexpr int Cn = 1000;   // classes
constexpr int Dn = 256;    // feature dim
constexpr float EPS = 1e-4f;

typedef __attribute__((ext_vector_type(8))) short bf16x8;
typedef __attribute__((ext_vector_type(4))) float f32x4;

static __device__ __forceinline__ unsigned short f2bf(float x) {
    union { float f; unsigned u; } v; v.f = x;
    return (unsigned short)((v.u + 0x7fffu + ((v.u >> 16) & 1u)) >> 16);
}
static __device__ __forceinline__ bf16x8 cvt8(const float4 lo, const float4 hi) {
    bf16x8 r;
    r[0] = (short)f2bf(lo.x); r[1] = (short)f2bf(lo.y);
    r[2] = (short)f2bf(lo.z); r[3] = (short)f2bf(lo.w);
    r[4] = (short)f2bf(hi.x); r[5] = (short)f2bf(hi.y);
    r[6] = (short)f2bf(hi.z); r[7] = (short)f2bf(hi.w);
    return r;
}
static __device__ __forceinline__ float bf2f(unsigned short h) {
    union { unsigned u; float f; } v; v.u = ((unsigned)h) << 16; return v.f;
}
// [R][256] bf16 tile, 512 B rows; XOR swizzle keeps b128 frag reads at the
// 8-cycle wave64 minimum (optimal) and staging writes ~4-way.
static __device__ __forceinline__ char* tile_p(unsigned short* b, int row, int kbyte) {
    return (char*)b + row * 512 + (kbyte ^ ((row & 7) << 4));
}
static __device__ __forceinline__ const char* tile_cp(const unsigned short* b, int row, int kbyte) {
    return (const char*)b + row * 512 + (kbyte ^ ((row & 7) << 4));
}

// ---------------------------------------------------------------------------
// Fused v3: 256 blocks x 512 threads (8 waves = 2 waves/SIMD).
// Block (r,c) computes out[64x64] tile at (r*64, c*64):
//   A: z/mu row-stripes -> bf16 regs (per wave: 16 z rows + 16 mu rows)
//   B: F^T staged bf16 in LDS, 128 cols per slice (2 slices, 4 barriers)
//   Y=z@F, U=mu@F -> LDS (swizzled); row norms from f32 accs in-register
//   D: 64x64 NT MFMA + fused bias epilogue.
__global__ __launch_bounds__(512, 2) void lda_fused3(const float* __restrict__ z,
                                                     const float* __restrict__ mu,
                                                     const float* __restrict__ logits,
                                                     const float* __restrict__ F,
                                                     float* __restrict__ out) {
    __shared__ unsigned short Ftl[128 * 256];  // 64 KB  [c_local][k]
    __shared__ unsigned short Yl[64 * 256];    // 32 KB
    __shared__ unsigned short Ul[64 * 256];    // 32 KB
    __shared__ float nY[2][64], nU[2][64], zn[64], mn[64];
    __shared__ float rowbias[64], colbias[64];

    const int bid = blockIdx.x, tid = threadIdx.x;
    const int row0 = (bid >> 4) * 64;   // z rows
    const int col0 = (bid & 15) * 64;   // classes
    const int lane = tid & 63, w = tid >> 6;
    const int wl = w & 3, wg = w >> 2;
    const int la = lane & 15, kg = lane >> 4;

    // ---- A preload: 16 z rows + 16 mu rows per wave -> bf16 regs
    const int zrow = row0 + wl * 16 + la;
    const int mrow = min(col0 + wl * 16 + la, Cn - 1);
    const float* zp = &z[(size_t)zrow * Dn];
    const float* mp = &mu[(size_t)mrow * Dn];
    bf16x8 az[8], am[8];
#pragma unroll
    for (int kt = 0; kt < 8; ++kt) {
        const int k0 = kt * 32 + kg * 8;
        az[kt] = cvt8(*(const float4*)&zp[k0], *(const float4*)&zp[k0 + 4]);
        am[kt] = cvt8(*(const float4*)&mp[k0], *(const float4*)&mp[k0 + 4]);
    }

    // ---- LSE: only wave 1 (the colbias wave) needs it; shuffle-only
    float lse = 0.f;
    if (w == 1) {
        float mx = -INFINITY;
        for (int i = lane; i < Cn; i += 64) mx = fmaxf(mx, logits[i]);
#pragma unroll
        for (int off = 32; off > 0; off >>= 1) mx = fmaxf(mx, __shfl_xor(mx, off));
        float sm = 0.f;
        for (int i = lane; i < Cn; i += 64) sm += expf(logits[i] - mx);
#pragma unroll
        for (int off = 32; off > 0; off >>= 1) sm += __shfl_xor(sm, off);
        lse = mx + logf(sm);
    }

    // ---- eps-norms of bf16(z/mu) rows from regs (reduce over kg lane-bits)
    {
        float s0 = 0.f, s1 = 0.f;
#pragma unroll
        for (int kt = 0; kt < 8; ++kt)
#pragma unroll
            for (int j = 0; j < 8; ++j) {
                const float a = bf2f((unsigned short)az[kt][j]); s0 = fmaf(a, a, s0);
                const float b = bf2f((unsigned short)am[kt][j]); s1 = fmaf(b, b, s1);
            }
        s0 += __shfl_xor(s0, 16); s0 += __shfl_xor(s0, 32);
        s1 += __shfl_xor(s1, 16); s1 += __shfl_xor(s1, 32);
        if (wg == 0 && kg == 0) {
            zn[wl * 16 + la] = s0;
            mn[wl * 16 + la] = s1;
        }
    }

    // ---- phase B: two 128-col slices of F
    float ny[4] = {0.f, 0.f, 0.f, 0.f}, nu[4] = {0.f, 0.f, 0.f, 0.f};
#pragma unroll 1
    for (int s = 0; s < 2; ++s) {
        __syncthreads();   // Ftl free (prev consumers done)
        {   // stage: thread covers cols (tid&3)*32..+32 at rows 2kp,2kp+1
            const int kp = tid >> 2;
            const int cb = (tid & 3) * 32;
            const float* f0 = &F[(size_t)(2 * kp) * Dn + s * 128 + cb];
            const float* f1 = f0 + Dn;
#pragma unroll
            for (int p = 0; p < 8; ++p) {
                const float4 r0 = *(const float4*)&f0[p * 4];
                const float4 r1 = *(const float4*)&f1[p * 4];
                const float* a0 = (const float*)&r0;
                const float* a1 = (const float*)&r1;
#pragma unroll
                for (int e = 0; e < 4; ++e) {
                    const int cl = cb + p * 4 + e;
                    ushort2 v; v.x = f2bf(a0[e]); v.y = f2bf(a1[e]);
                    *(ushort2*)((char*)Ftl + 512 * cl + ((4 * kp) ^ ((cl & 7) << 4))) = v;
                }
            }
        }
        __syncthreads();

#pragma unroll
        for (int ctl = 0; ctl < 2; ++ctl) {
            const int clb = (wg * 2 + ctl) * 32;   // c_local base (this wave-group)
            bf16x8 b0[8], b1[8];
#pragma unroll
            for (int kt = 0; kt < 8; ++kt) {
                const int kb = kt * 64 + kg * 16;
                b0[kt] = *(const bf16x8*)tile_cp(Ftl, clb + la, kb);
                b1[kt] = *(const bf16x8*)tile_cp(Ftl, clb + 16 + la, kb);
            }
            f32x4 aY0 = {0.f,0.f,0.f,0.f}, aY1 = {0.f,0.f,0.f,0.f};
            f32x4 aU0 = {0.f,0.f,0.f,0.f}, aU1 = {0.f,0.f,0.f,0.f};
#pragma unroll
            for (int kt = 0; kt < 8; ++kt) {
                aY0 = __builtin_amdgcn_mfma_f32_16x16x32_bf16(az[kt], b0[kt], aY0, 0, 0, 0);
                aY1 = __builtin_amdgcn_mfma_f32_16x16x32_bf16(az[kt], b1[kt], aY1, 0, 0, 0);
                aU0 = __builtin_amdgcn_mfma_f32_16x16x32_bf16(am[kt], b0[kt], aU0, 0, 0, 0);
                aU1 = __builtin_amdgcn_mfma_f32_16x16x32_bf16(am[kt], b1[kt], aU1, 0, 0, 0);
            }
            const int wcol = s * 128 + clb;        // global W col (grp0 base)
            const int rw0 = wl * 16 + kg * 4;
#pragma unroll
            for (int j = 0; j < 4; ++j) {
                const int row = rw0 + j;
                *(unsigned short*)tile_p(Yl, row, (wcol + la) * 2)      = f2bf(aY0[j]);
                *(unsigned short*)tile_p(Yl, row, (wcol + 16 + la) * 2) = f2bf(aY1[j]);
                *(unsigned short*)tile_p(Ul, row, (wcol + la) * 2)      = f2bf(aU0[j]);
                *(unsigned short*)tile_p(Ul, row, (wcol + 16 + la) * 2) = f2bf(aU1[j]);
                ny[j] = fmaf(aY0[j], aY0[j], ny[j]); ny[j] = fmaf(aY1[j], aY1[j], ny[j]);
                nu[j] = fmaf(aU0[j], aU0[j], nu[j]); nu[j] = fmaf(aU1[j], aU1[j], nu[j]);
            }
        }
    }

    // ---- norm reduce over the 16 la-lanes; write per-wave-group partials
#pragma unroll
    for (int j = 0; j < 4; ++j) {
#pragma unroll
        for (int m = 1; m < 16; m <<= 1) {
            ny[j] += __shfl_xor(ny[j], m);
            nu[j] += __shfl_xor(nu[j], m);
        }
    }
    if (la == 0) {
#pragma unroll
        for (int j = 0; j < 4; ++j) {
            nY[wg][wl * 16 + kg * 4 + j] = ny[j];
            nU[wg][wl * 16 + kg * 4 + j] = nu[j];
        }
    }
    __syncthreads();

    if (tid < 64) {
        rowbias[tid] = -0.5f * (nY[0][tid] + nY[1][tid] + EPS * zn[tid]);
    } else if (tid < 128) {
        const int lc = tid - 64, c = col0 + lc;
        colbias[lc] = (c < Cn)
            ? logits[c] - lse - 0.5f * (nU[0][lc] + nU[1][lc] + EPS * mn[lc])
            : 0.f;
    }
    __syncthreads();

    // ---- phase D: per wave a 16x32 output sub-tile
    const int wr2 = wl * 16, wc2 = wg * 32;
    bf16x8 a[8], bb0[8], bb1[8];
#pragma unroll
    for (int kt = 0; kt < 8; ++kt) {
        const int kb = kt * 64 + kg * 16;
        a[kt]   = *(const bf16x8*)tile_cp(Yl, wr2 + la, kb);
        bb0[kt] = *(const bf16x8*)tile_cp(Ul, wc2 + la, kb);
        bb1[kt] = *(const bf16x8*)tile_cp(Ul, wc2 + 16 + la, kb);
    }
    f32x4 c0 = {0.f,0.f,0.f,0.f}, c1 = {0.f,0.f,0.f,0.f};
#pragma unroll
    for (int kt = 0; kt < 8; ++kt) {
        c0 = __builtin_amdgcn_mfma_f32_16x16x32_bf16(a[kt], bb0[kt], c0, 0, 0, 0);
        c1 = __builtin_amdgcn_mfma_f32_16x16x32_bf16(a[kt], bb1[kt], c1, 0, 0, 0);
    }

    // C/D layout: col = lane&15, row = kg*4 + j
#pragma unroll
    for (int j = 0; j < 4; ++j) {
        const int rl = wr2 + kg * 4 + j;
        const int gr = row0 + rl;
        const float rb = rowbias[rl];
        const int gc0 = col0 + wc2 + la;
        const int gc1 = gc0 + 16;
        if (gc0 < Cn) out[(size_t)gr * Cn + gc0] = c0[j] + rb + colbias[wc2 + la];
        if (gc1 < Cn) out[(size_t)gr * Cn + gc1] = c1[j] + rb + colbias[wc2 + 16 + la];
    }
}

// ---------------------------------------------------------------------------
extern "C" void kernel_launch(void* const* d_in, const int* in_sizes, int n_in,
                              void* d_out, int out_size, void* d_ws, size_t ws_size,
                              hipStream_t stream) {
    const float* z      = (const float*)d_in[0];   // [1024][256]
    const float* mu     = (const float*)d_in[1];   // [1000][256]
    const float* logits = (const float*)d_in[2];   // [1000]
    const float* F      = (const float*)d_in[3];   // [256][256]
    float* out = (float*)d_out;                    // [1024][1000]

    lda_fused3<<<dim3(256), dim3(512), 0, stream>>>(z, mu, logits, F, out);
}

// Round 10
// 22.629 us; speedup vs baseline: 1.8050x; 1.3804x over previous
//
#include <hip/hip_runtime.h>
#include <hip/hip_bf16.h>
#include <math.h>

constexpr int Bn = 1024;   // batch
constexpr int Cn = 1000;   // classes
constexpr int Dn = 256;    // feature dim
constexpr float EPS = 1e-4f;

typedef __attribute__((ext_vector_type(8))) short bf16x8;
typedef __attribute__((ext_vector_type(4))) float f32x4;

static __device__ __forceinline__ unsigned short f2bf(float x) {
    union { float f; unsigned u; } v; v.f = x;
    return (unsigned short)((v.u + 0x7fffu + ((v.u >> 16) & 1u)) >> 16);
}
static __device__ __forceinline__ float bf2f(unsigned short h) {
    union { unsigned u; float f; } v; v.u = ((unsigned)h) << 16; return v.f;
}
static __device__ __forceinline__ bf16x8 cvt8(const float4 lo, const float4 hi) {
    bf16x8 r;
    r[0] = (short)f2bf(lo.x); r[1] = (short)f2bf(lo.y);
    r[2] = (short)f2bf(lo.z); r[3] = (short)f2bf(lo.w);
    r[4] = (short)f2bf(hi.x); r[5] = (short)f2bf(hi.y);
    r[6] = (short)f2bf(hi.z); r[7] = (short)f2bf(hi.w);
    return r;
}

// ---------------------------------------------------------------------------
// K1: Wb = bf16(G @ F) with G = [z ; mu_clamped] (2048 rows).
// 513 blocks x 256 thr; each wave owns a 16x16 W-tile (single 8-MFMA chain).
// Also emits rn_part[row][ct] = ||Wb_row over ct's 16 cols||^2 (bf16-rounded),
// epsn[row] = EPS*||G_row||^2 (bf16-rounded inputs), and lse (block 512).
__global__ __launch_bounds__(256) void w_kernel2(const float* __restrict__ z,
                                                 const float* __restrict__ mu,
                                                 const float* __restrict__ logits,
                                                 const float* __restrict__ F,
                                                 unsigned short* __restrict__ Wb,      // [2048][256]
                                                 float* __restrict__ rn_part,          // [2048][16]
                                                 float* __restrict__ epsn,             // [2048]
                                                 float* __restrict__ lse_p) {
    const int bid = blockIdx.x, tid = threadIdx.x;

    if (bid == 512) {   // LSE (wave 0 only, shuffle-only)
        if (tid < 64) {
            float mx = -INFINITY;
            for (int i = tid; i < Cn; i += 64) mx = fmaxf(mx, logits[i]);
#pragma unroll
            for (int off = 32; off > 0; off >>= 1) mx = fmaxf(mx, __shfl_xor(mx, off));
            float sm = 0.f;
            for (int i = tid; i < Cn; i += 64) sm += expf(logits[i] - mx);
#pragma unroll
            for (int off = 32; off > 0; off >>= 1) sm += __shfl_xor(sm, off);
            if (tid == 0) *lse_p = mx + logf(sm);
        }
        return;
    }

    const int row0 = (bid >> 3) * 32;   // 64 row-groups over 2048 G rows
    const int col0 = (bid & 7) * 32;    // 8 col-groups
    const int lane = tid & 63, w = tid >> 6;
    const int la = lane & 15, kg = lane >> 4;
    const int wr = (w >> 1) * 16, wc = (w & 1) * 16;
    const int ct = (bid & 7) * 2 + (w & 1);      // 16-col tile index 0..15

    // A fragments: row = la, k = kg*8 (+ 8 per kt)
    const int grow = row0 + wr + la;
    const float* ap = (grow < 1024) ? &z[(size_t)grow * Dn]
                                    : &mu[(size_t)min(grow - 1024, Cn - 1) * Dn];
    bf16x8 af[8];
    float zs = 0.f;   // this lane's slice of ||G_row(la)||^2 (bf16 values)
#pragma unroll
    for (int kt = 0; kt < 8; ++kt) {
        const int k0 = kt * 32 + kg * 8;
        af[kt] = cvt8(*(const float4*)&ap[k0], *(const float4*)&ap[k0 + 4]);
#pragma unroll
        for (int j = 0; j < 8; ++j) {
            const float v = bf2f((unsigned short)af[kt][j]);
            zs = fmaf(v, v, zs);
        }
    }

    // B fragments: col = la (coalesced across the 16 frag lanes), MFMA chain
    const int bcol = col0 + wc + la;
    f32x4 acc = {0.f, 0.f, 0.f, 0.f};
#pragma unroll
    for (int kt = 0; kt < 8; ++kt) {
        const int k0 = kt * 32 + kg * 8;
        bf16x8 bf;
#pragma unroll
        for (int j = 0; j < 8; ++j) bf[j] = (short)f2bf(F[(size_t)(k0 + j) * Dn + bcol]);
        acc = __builtin_amdgcn_mfma_f32_16x16x32_bf16(af[kt], bf, acc, 0, 0, 0);
    }

    // C/D: col = la, row = kg*4 + j.  Store Wb + norm partials (rounded).
    float np[4];
#pragma unroll
    for (int j = 0; j < 4; ++j) {
        const unsigned short h = f2bf(acc[j]);
        Wb[(size_t)(row0 + wr + kg * 4 + j) * Dn + bcol] = h;
        const float v = bf2f(h);
        float s = v * v;
        s += __shfl_xor(s, 1); s += __shfl_xor(s, 2);
        s += __shfl_xor(s, 4); s += __shfl_xor(s, 8);
        np[j] = s;
    }
    if (la == 0) {
#pragma unroll
        for (int j = 0; j < 4; ++j)
            rn_part[(size_t)(row0 + wr + kg * 4 + j) * 16 + ct] = np[j];
    }

    // eps-norm: reduce zs over kg lane-bits; write once per row
    zs += __shfl_xor(zs, 16);
    zs += __shfl_xor(zs, 32);
    if ((bid & 7) == 0 && (w & 1) == 0 && kg == 0)
        epsn[row0 + wr + la] = EPS * zs;
}

// ---------------------------------------------------------------------------
// K2: out[b][c] = Wb_Y(b).Wb_U(c) + rowbias[b] + colbias[c]
// 512 blocks x 256 thr; wave = 16x32 output tile (2 MFMA chains).
// Biases assembled from rn_part/epsn/logits/lse in one barrier.
__global__ __launch_bounds__(256) void out_kernel(const unsigned short* __restrict__ Wb,
                                                  const float* __restrict__ rn_part,
                                                  const float* __restrict__ epsn,
                                                  const float* __restrict__ logits,
                                                  const float* __restrict__ lse_p,
                                                  float* __restrict__ out) {
    __shared__ float rowbias[32], colbias[64];
    const int bid = blockIdx.x, tid = threadIdx.x;
    const int row0 = (bid >> 4) * 32;   // 32 row-groups over 1024 z rows
    const int col0 = (bid & 15) * 64;   // 16 col-groups over 1024 (guard >=1000)

    if (tid < 32) {
        const int r = row0 + tid;
        const float4* p = (const float4*)&rn_part[(size_t)r * 16];
        const float4 a = p[0], b = p[1], c = p[2], d = p[3];
        const float s = a.x + a.y + a.z + a.w + b.x + b.y + b.z + b.w +
                        c.x + c.y + c.z + c.w + d.x + d.y + d.z + d.w;
        rowbias[tid] = -0.5f * (s + epsn[r]);
    } else if (tid < 96) {
        const int lc = tid - 32, c = col0 + lc;
        float v = 0.f;
        if (c < Cn) {
            const int r = 1024 + c;
            const float4* p = (const float4*)&rn_part[(size_t)r * 16];
            const float4 a = p[0], b = p[1], cc = p[2], d = p[3];
            const float s = a.x + a.y + a.z + a.w + b.x + b.y + b.z + b.w +
                            cc.x + cc.y + cc.z + cc.w + d.x + d.y + d.z + d.w;
            v = logits[c] - *lse_p - 0.5f * (s + epsn[r]);
        }
        colbias[lc] = v;
    }
    __syncthreads();

    const int lane = tid & 63, w = tid >> 6;
    const int la = lane & 15, kg = lane >> 4;
    const int wr = (w >> 1) * 16, wc = (w & 1) * 32;

    const bf16x8* pa  = (const bf16x8*)&Wb[(size_t)(row0 + wr + la) * Dn + kg * 8];
    const bf16x8* pb0 = (const bf16x8*)&Wb[(size_t)(1024 + col0 + wc + la) * Dn + kg * 8];
    const bf16x8* pb1 = pb0 + 512;   // +16 rows (16 * 256 / 8 units)

    f32x4 c0 = {0.f, 0.f, 0.f, 0.f}, c1 = {0.f, 0.f, 0.f, 0.f};
#pragma unroll
    for (int kt = 0; kt < 8; ++kt) {
        const bf16x8 a  = pa[kt * 4];
        const bf16x8 b0 = pb0[kt * 4];
        const bf16x8 b1 = pb1[kt * 4];
        c0 = __builtin_amdgcn_mfma_f32_16x16x32_bf16(a, b0, c0, 0, 0, 0);
        c1 = __builtin_amdgcn_mfma_f32_16x16x32_bf16(a, b1, c1, 0, 0, 0);
    }

    // C/D: col = la, row = kg*4 + j
#pragma unroll
    for (int j = 0; j < 4; ++j) {
        const int rl = wr + kg * 4 + j;
        const int gr = row0 + rl;
        const float rb = rowbias[rl];
        const int gc0 = col0 + wc + la;
        const int gc1 = gc0 + 16;
        if (gc0 < Cn) out[(size_t)gr * Cn + gc0] = c0[j] + rb + colbias[wc + la];
        if (gc1 < Cn) out[(size_t)gr * Cn + gc1] = c1[j] + rb + colbias[wc + 16 + la];
    }
}

// ---------------------------------------------------------------------------
extern "C" void kernel_launch(void* const* d_in, const int* in_sizes, int n_in,
                              void* d_out, int out_size, void* d_ws, size_t ws_size,
                              hipStream_t stream) {
    const float* z      = (const float*)d_in[0];   // [1024][256]
    const float* mu     = (const float*)d_in[1];   // [1000][256]
    const float* logits = (const float*)d_in[2];   // [1000]
    const float* F      = (const float*)d_in[3];   // [256][256]
    float* out = (float*)d_out;                    // [1024][1000]

    char* ws = (char*)d_ws;
    unsigned short* Wb = (unsigned short*)(ws);            // 1 MB   [2048][256] bf16
    float* rn_part = (float*)(ws + (1 << 20));             // 128 KB [2048][16]
    float* epsn    = (float*)(ws + (1 << 20) + (128 << 10)); // 8 KB [2048]
    float* lse     = epsn + 2048;                          // 4 B

    w_kernel2<<<dim3(513), dim3(256), 0, stream>>>(z, mu, logits, F, Wb, rn_part, epsn, lse);
    out_kernel<<<dim3(512), dim3(256), 0, stream>>>(Wb, rn_part, epsn, logits, lse, out);
}